// Round 13
// baseline (1812.244 us; speedup 1.0000x reference)
//
#include <hip/hip_runtime.h>

#define HH 50
#define NGATE 200      // 4*H gate rows
#define NB 8           // batch elements per block
#define TT 512
#define NTH 1024       // 16 waves -> 4 waves/SIMD, all co-resident (single workgroup)
#define NTILES 13      // ceil(200/16)
#define A0S 72         // shorts/row: 64 k-slots (54 used: h|x|1) + 8 pad = 144B
#define A1S 136        // shorts/row: 128 k-slots (101 used: h1|hB|1) + 8 pad = 272B
#define GS 20          // g row stride (floats), rows indexed by gate n
#define NFRAG (NTILES * 12)   // 12 fragment slots per N-tile

typedef __attribute__((ext_vector_type(8))) short short8;
typedef __attribute__((ext_vector_type(4))) float f32x4;

__device__ __forceinline__ unsigned short f2bf(float f) {
    unsigned int u = __float_as_uint(f);
    u += 0x7FFFu + ((u >> 16) & 1u);
    return (unsigned short)(u >> 16);
}
__device__ __forceinline__ float bf2f(unsigned short s) {
    return __uint_as_float(((unsigned int)s) << 16);
}
__device__ __forceinline__ float fast_sigmoid(float v) {
    v = fminf(fmaxf(v, -30.f), 30.f);
    return 1.f / (1.f + __expf(-v));
}
__device__ __forceinline__ float fast_tanh(float v) {
    v = fminf(fmaxf(v, -15.f), 15.f);
    float e = __expf(2.f * v);
    return (e - 1.f) / (e + 1.f);
}
__device__ __forceinline__ float cell_h(float pi, float pf, float pg, float po, float& c) {
    float ii = fast_sigmoid(pi), ff = fast_sigmoid(pf);
    float gg = fast_tanh(pg),    oo = fast_sigmoid(po);
    c = ff * c + ii * gg;
    return oo * fast_tanh(c);
}

// ---------------- prep kernel: build split-bf16 B-fragments in d_ws ----------------
__global__ void prep_frags(
    const float* __restrict__ W_ih0, const float* __restrict__ W_hh0,
    const float* __restrict__ b_ih0, const float* __restrict__ b_hh0,
    const float* __restrict__ W_ih1, const float* __restrict__ W_hh1,
    const float* __restrict__ b_ih1, const float* __restrict__ b_hh1,
    unsigned short* __restrict__ ws)
{
    int idx = blockIdx.x * blockDim.x + threadIdx.x;
    if (idx >= NFRAG * 64) return;
    const int lane = idx & 63;
    const int fid  = idx >> 6;
    const int nt   = fid / 12;
    const int slot = fid - nt * 12;
    const int n    = nt * 16 + (lane & 15);
    const int q4   = lane >> 4;
    const int layer = (slot < 4) ? 0 : 1;
    const int s     = (slot < 4) ? slot : (slot - 4);
    const int kt    = s >> 1;
    const int ishi  = !(s & 1);

    short8 v;
    #pragma unroll
    for (int jj = 0; jj < 8; ++jj) {
        int k = kt * 32 + q4 * 8 + jj;
        float w = 0.f;
        if (n < NGATE) {
            if (layer == 0) {
                if (k < 50)       w = W_hh0[n * 50 + k];
                else if (k < 53)  w = W_ih0[n * 3 + (k - 50)];
                else if (k == 53) w = b_ih0[n] + b_hh0[n];
            } else {
                if (k < 50)        w = W_ih1[n * 50 + k];
                else if (k < 100)  w = W_hh1[n * 50 + (k - 50)];
                else if (k == 100) w = b_ih1[n] + b_hh1[n];
            }
        }
        unsigned short h = f2bf(w);
        v[jj] = (short)(ishi ? h : f2bf(w - bf2f(h)));
    }
    *(short8*)&ws[((size_t)fid * 64 + lane) * 8] = v;
}

// ---------------- main kernel: 16-wave single block, 4 waves/SIMD guaranteed ----------------
// Round-12 lesson: inter-block co-residency never materializes (2 x 512t blocks at
// 128 VGPR serialized; occupancy stuck at 23%). A SINGLE 1024-thread workgroup
// sidesteps the block scheduler: its 16 waves are co-resident by construction.
// Round-11 lesson: waves_per_eu(4,4) made the allocator pick 64 VGPRs (it targets
// ~2x the requested min) -> spills. launch_bounds(1024, 2) requests min=2 -> the
// allocator targets 4 waves/EU = 128 VGPRs, which the 1024-thread block size also
// structurally caps. Gates: VGPR==128, WRITE ~24KB, FETCH ~7MB, Occupancy ~50%.
__global__ __launch_bounds__(NTH, 2) void lstm_mfma_v11(
    const float* __restrict__ x,
    const unsigned short* __restrict__ ws,
    const float* __restrict__ fc_w, const float* __restrict__ fc_b,
    float* __restrict__ out)
{
    __shared__ unsigned short A0hi[16 * A0S], A0lo[16 * A0S];
    __shared__ unsigned short A1hi[16 * A1S], A1lo[16 * A1S];
    __shared__ float g0[208 * GS];     // layer0 gate preacts [n][batch]
    __shared__ float g1[208 * GS];     // layer1 gate preacts (one step behind)
    __shared__ float hBf[NB * 52];     // final-step hB (fp32) for the FC

    const int tid = threadIdx.x;
    const int n16 = tid & 15;
    const int q4  = (tid >> 4) & 3;
    const int wid = tid >> 6;          // wave 0..15
    const int lane = tid & 63;
    const int b0  = blockIdx.x * NB;

    // ---- zero A state ----
    for (int i = tid; i < 16 * A0S; i += NTH) { A0hi[i] = 0; A0lo[i] = 0; }
    for (int i = tid; i < 16 * A1S; i += NTH) { A1hi[i] = 0; A1lo[i] = 0; }
    __syncthreads();

    if (tid < NB) {
        A0hi[tid * A0S + 53]  = 0x3F80;   // bf16 1.0 (bias column)
        A1hi[tid * A1S + 100] = 0x3F80;
    }

    // ---- B-fragments from ws ----
    // L0 MFMA waves 0..5:  tiles nt = wid + 6*i, i<3  (wave0: 3 tiles, others 2)
    // L1 MFMA waves 6..15: tiles nt = (wid-6) + 10*i, i<2 (waves 6-8: 2, 9-15: 1)
    const short8* wsf = (const short8*)ws;
    short8 f0h[3][2], f0l[3][2];
    short8 f1h[2][4], f1l[2][4];
    if (wid < 6) {
        #pragma unroll
        for (int i = 0; i < 3; ++i) {
            const int nt = wid + 6 * i;
            const bool nv = (nt < NTILES);
            const size_t gbase = (size_t)(nv ? nt : 0) * 12 * 64 + lane;
            #pragma unroll
            for (int kt = 0; kt < 2; ++kt) {
                f0h[i][kt] = nv ? wsf[gbase + (size_t)(kt * 2 + 0) * 64] : short8{};
                f0l[i][kt] = nv ? wsf[gbase + (size_t)(kt * 2 + 1) * 64] : short8{};
            }
        }
    } else {
        #pragma unroll
        for (int i = 0; i < 2; ++i) {
            const int nt = (wid - 6) + 10 * i;
            const bool nv = (nt < NTILES);
            const size_t gbase = (size_t)(nv ? nt : 0) * 12 * 64 + lane;
            #pragma unroll
            for (int kt = 0; kt < 4; ++kt) {
                f1h[i][kt] = nv ? wsf[gbase + (size_t)(4 + kt * 2 + 0) * 64] : short8{};
                f1l[i][kt] = nv ? wsf[gbase + (size_t)(4 + kt * 2 + 1) * 64] : short8{};
            }
        }
    }

    // ---- cell roles ----
    const int cb0 = tid & 7,  up0 = tid >> 3;          // L0 cells: tid < 200
    const int t2  = tid - 512;
    const int cb1 = t2 & 7,   up1 = t2 >> 3;           // L1 cells: 512 <= tid < 712
    float c0a = 0.f, c0b = 0.f, cBa = 0.f, cBb = 0.f;

    // ---- x-writer role: threads 960..983 (wave 15, light frag load) ----
    float xv = 0.f;
    size_t xbase = 0;
    int xb = 0, xc = 0;
    if (tid >= 960 && tid < 960 + NB * 3) {
        int i = tid - 960;
        xb = i / 3; xc = i - xb * 3;
        xbase = (size_t)(b0 + xb) * (TT * 3);
        float x0 = x[xbase + xc];                    // t = 0
        unsigned short h = f2bf(x0);
        A0hi[xb * A0S + 50 + xc] = h;
        A0lo[xb * A0S + 50 + xc] = f2bf(x0 - bf2f(h));
        xv = x[xbase + 3 + xc];                      // prefetch t = 1
    }
    __syncthreads();

    // ================= PIPELINED MAIN LOOP (TT+1 iterations) =================
    // iter t: phase M computes g0(t) [waves 0-5, t<TT] and g1(t-1) [waves 6-15, t>0];
    //         phase C computes h0(t) [t<TT] and hB(t-1) [t>0].
    for (int t = 0; t <= TT; ++t) {
        // -------- phase M --------
        if (wid < 6) {
            if (t < TT) {
                short8 a0h_[2], a0l_[2];
                #pragma unroll
                for (int kt = 0; kt < 2; ++kt) {
                    a0h_[kt] = *(const short8*)&A0hi[n16 * A0S + kt * 32 + q4 * 8];
                    a0l_[kt] = *(const short8*)&A0lo[n16 * A0S + kt * 32 + q4 * 8];
                }
                #pragma unroll
                for (int i = 0; i < 3; ++i) {
                    const int nt = wid + 6 * i;
                    if (nt < NTILES) {
                        f32x4 aa = {0.f,0.f,0.f,0.f}, ab = {0.f,0.f,0.f,0.f};
                        aa = __builtin_amdgcn_mfma_f32_16x16x32_bf16(a0h_[0], f0h[i][0], aa, 0, 0, 0);
                        aa = __builtin_amdgcn_mfma_f32_16x16x32_bf16(a0l_[0], f0h[i][0], aa, 0, 0, 0);
                        aa = __builtin_amdgcn_mfma_f32_16x16x32_bf16(a0h_[0], f0l[i][0], aa, 0, 0, 0);
                        ab = __builtin_amdgcn_mfma_f32_16x16x32_bf16(a0h_[1], f0h[i][1], ab, 0, 0, 0);
                        ab = __builtin_amdgcn_mfma_f32_16x16x32_bf16(a0l_[1], f0h[i][1], ab, 0, 0, 0);
                        ab = __builtin_amdgcn_mfma_f32_16x16x32_bf16(a0h_[1], f0l[i][1], ab, 0, 0, 0);
                        if (q4 < 2)   // batches 0..7
                            *(f32x4*)&g0[(nt * 16 + n16) * GS + q4 * 4] = aa + ab;
                    }
                }
            }
        } else {
            if (t > 0) {
                short8 a1h_[4], a1l_[4];
                #pragma unroll
                for (int kt = 0; kt < 4; ++kt) {
                    a1h_[kt] = *(const short8*)&A1hi[n16 * A1S + kt * 32 + q4 * 8];
                    a1l_[kt] = *(const short8*)&A1lo[n16 * A1S + kt * 32 + q4 * 8];
                }
                #pragma unroll
                for (int i = 0; i < 2; ++i) {
                    const int nt = (wid - 6) + 10 * i;
                    if (nt < NTILES) {
                        f32x4 aa = {0.f,0.f,0.f,0.f}, ab = {0.f,0.f,0.f,0.f};
                        #pragma unroll
                        for (int kt = 0; kt < 2; ++kt) {
                            aa = __builtin_amdgcn_mfma_f32_16x16x32_bf16(a1h_[kt], f1h[i][kt], aa, 0, 0, 0);
                            aa = __builtin_amdgcn_mfma_f32_16x16x32_bf16(a1l_[kt], f1h[i][kt], aa, 0, 0, 0);
                            aa = __builtin_amdgcn_mfma_f32_16x16x32_bf16(a1h_[kt], f1l[i][kt], aa, 0, 0, 0);
                        }
                        #pragma unroll
                        for (int kt = 2; kt < 4; ++kt) {
                            ab = __builtin_amdgcn_mfma_f32_16x16x32_bf16(a1h_[kt], f1h[i][kt], ab, 0, 0, 0);
                            ab = __builtin_amdgcn_mfma_f32_16x16x32_bf16(a1l_[kt], f1h[i][kt], ab, 0, 0, 0);
                            ab = __builtin_amdgcn_mfma_f32_16x16x32_bf16(a1h_[kt], f1l[i][kt], ab, 0, 0, 0);
                        }
                        if (q4 < 2)
                            *(f32x4*)&g1[(nt * 16 + n16) * GS + q4 * 4] = aa + ab;
                    }
                }
            }
        }
        __syncthreads();

        // -------- phase C --------
        if (tid < 200) {
            if (t < TT) {
                const int cu0 = 2 * up0, cu1 = cu0 + 1;
                float h0 = cell_h(g0[cu0 * GS + cb0],         g0[(cu0 + 50) * GS + cb0],
                                  g0[(cu0 + 100) * GS + cb0], g0[(cu0 + 150) * GS + cb0], c0a);
                float h1 = cell_h(g0[cu1 * GS + cb0],         g0[(cu1 + 50) * GS + cb0],
                                  g0[(cu1 + 100) * GS + cb0], g0[(cu1 + 150) * GS + cb0], c0b);
                unsigned short h0h = f2bf(h0), h1h = f2bf(h1);
                unsigned int vhi = (unsigned int)h0h | ((unsigned int)h1h << 16);
                unsigned int vlo = (unsigned int)f2bf(h0 - bf2f(h0h))
                                 | ((unsigned int)f2bf(h1 - bf2f(h1h)) << 16);
                *(unsigned int*)&A0hi[cb0 * A0S + cu0] = vhi;   // layer0 recurrent input
                *(unsigned int*)&A0lo[cb0 * A0S + cu0] = vlo;
                *(unsigned int*)&A1hi[cb0 * A1S + cu0] = vhi;   // layer1 input (consumed M(t+1))
                *(unsigned int*)&A1lo[cb0 * A1S + cu0] = vlo;
            }
        } else if (tid >= 512 && tid < 712) {
            if (t > 0) {
                const int cu0 = 2 * up1, cu1 = cu0 + 1;
                float h0 = cell_h(g1[cu0 * GS + cb1],         g1[(cu0 + 50) * GS + cb1],
                                  g1[(cu0 + 100) * GS + cb1], g1[(cu0 + 150) * GS + cb1], cBa);
                float h1 = cell_h(g1[cu1 * GS + cb1],         g1[(cu1 + 50) * GS + cb1],
                                  g1[(cu1 + 100) * GS + cb1], g1[(cu1 + 150) * GS + cb1], cBb);
                unsigned short h0h = f2bf(h0), h1h = f2bf(h1);
                unsigned int vhi = (unsigned int)h0h | ((unsigned int)h1h << 16);
                unsigned int vlo = (unsigned int)f2bf(h0 - bf2f(h0h))
                                 | ((unsigned int)f2bf(h1 - bf2f(h1h)) << 16);
                *(unsigned int*)&A1hi[cb1 * A1S + 50 + cu0] = vhi;  // recurrent hB
                *(unsigned int*)&A1lo[cb1 * A1S + 50 + cu0] = vlo;
                if (t == TT) {
                    hBf[cb1 * 52 + cu0] = h0;
                    hBf[cb1 * 52 + cu1] = h1;
                }
            }
        } else if (tid >= 960 && tid < 960 + NB * 3) {
            unsigned short h = f2bf(xv);                   // x(t+1) (clamped at tail; harmless)
            A0hi[xb * A0S + 50 + xc] = h;
            A0lo[xb * A0S + 50 + xc] = f2bf(xv - bf2f(h));
            int tn = (t + 2 < TT) ? (t + 2) : (TT - 1);
            xv = x[xbase + tn * 3 + xc];
        }
        __syncthreads();
    }

    // ======== final FC ========
    if (tid < NB * 3) {
        int bb = tid / 3, o = tid - bb * 3;
        float a = fc_b[o];
        #pragma unroll
        for (int uu = 0; uu < HH; ++uu)
            a += hBf[bb * 52 + uu] * fc_w[o * HH + uu];
        out[(size_t)(b0 + bb) * 3 + o] = a;
    }
}

extern "C" void kernel_launch(void* const* d_in, const int* in_sizes, int n_in,
                              void* d_out, int out_size, void* d_ws, size_t ws_size,
                              hipStream_t stream) {
    const float* x     = (const float*)d_in[0];
    const float* W_ih0 = (const float*)d_in[1];
    const float* W_hh0 = (const float*)d_in[2];
    const float* b_ih0 = (const float*)d_in[3];
    const float* b_hh0 = (const float*)d_in[4];
    const float* W_ih1 = (const float*)d_in[5];
    const float* W_hh1 = (const float*)d_in[6];
    const float* b_ih1 = (const float*)d_in[7];
    const float* b_hh1 = (const float*)d_in[8];
    const float* fc_w  = (const float*)d_in[9];
    const float* fc_b  = (const float*)d_in[10];
    float* out = (float*)d_out;
    unsigned short* ws = (unsigned short*)d_ws;   // needs NFRAG*64*16 B = 156 KB

    const int prepN = NFRAG * 64;
    prep_frags<<<(prepN + 255) / 256, 256, 0, stream>>>(
        W_ih0, W_hh0, b_ih0, b_hh0, W_ih1, W_hh1, b_ih1, b_hh1, ws);

    const int B = 2048;
    dim3 grid(B / NB), block(NTH);
    lstm_mfma_v11<<<grid, block, 0, stream>>>(x, ws, fc_w, fc_b, out);
}

// Round 14
// 1254.560 us; speedup vs baseline: 1.4445x; 1.4445x over previous
//
#include <hip/hip_runtime.h>

#define HH 50
#define NGATE 200      // 4*H gate rows (unit-major permuted: n' = 4*unit + gate)
#define NB 8           // batch elements per block
#define TT 512
#define NTH 512
#define NTILES 13      // ceil(200/16); tile nt covers units 4nt..4nt+3
#define A0S 72         // shorts/row: 64 k-slots (54 used: h|x|1) + 8 pad = 144B
#define A1S 136        // shorts/row: 128 k-slots (101 used: h1|hB|1) + 8 pad = 272B
#define NFRAG (NTILES * 12)   // 12 fragment slots per N-tile

typedef __attribute__((ext_vector_type(8))) short short8;
typedef __attribute__((ext_vector_type(4))) float f32x4;

__device__ __forceinline__ unsigned short f2bf(float f) {
    unsigned int u = __float_as_uint(f);
    u += 0x7FFFu + ((u >> 16) & 1u);
    return (unsigned short)(u >> 16);
}
__device__ __forceinline__ float bf2f(unsigned short s) {
    return __uint_as_float(((unsigned int)s) << 16);
}
__device__ __forceinline__ float fast_sigmoid(float v) {
    v = fminf(fmaxf(v, -30.f), 30.f);
    return 1.f / (1.f + __expf(-v));
}
__device__ __forceinline__ float fast_tanh(float v) {
    v = fminf(fmaxf(v, -15.f), 15.f);
    float e = __expf(2.f * v);
    return (e - 1.f) / (e + 1.f);
}

// ---------------- prep kernel: unit-major-permuted split-bf16 B-fragments ----------------
// Gate rows permuted n' = 4*unit + gate (orig = gate*50 + unit), so one MFMA
// 16-column group = 4 units x 4 gates -> the cell update becomes a 4x4 lane
// transpose inside the MFMA wave (kills the g-matrix LDS roundtrip + barrier).
// slot map per N-tile nt: 0..3 = L0 kt{0,1} x {hi,lo}; 4..11 = L1 kt{0..3} x {hi,lo}
__global__ void prep_frags(
    const float* __restrict__ W_ih0, const float* __restrict__ W_hh0,
    const float* __restrict__ b_ih0, const float* __restrict__ b_hh0,
    const float* __restrict__ W_ih1, const float* __restrict__ W_hh1,
    const float* __restrict__ b_ih1, const float* __restrict__ b_hh1,
    unsigned short* __restrict__ ws)
{
    int idx = blockIdx.x * blockDim.x + threadIdx.x;
    if (idx >= NFRAG * 64) return;
    const int lane = idx & 63;
    const int fid  = idx >> 6;
    const int nt   = fid / 12;
    const int slot = fid - nt * 12;
    const int np   = nt * 16 + (lane & 15);        // permuted row index
    const int orig = (np & 3) * 50 + (np >> 2);    // original gate-major row
    const int q4   = lane >> 4;
    const int layer = (slot < 4) ? 0 : 1;
    const int s     = (slot < 4) ? slot : (slot - 4);
    const int kt    = s >> 1;
    const int ishi  = !(s & 1);

    short8 v;
    #pragma unroll
    for (int jj = 0; jj < 8; ++jj) {
        int k = kt * 32 + q4 * 8 + jj;
        float w = 0.f;
        if (np < NGATE) {
            if (layer == 0) {
                if (k < 50)       w = W_hh0[orig * 50 + k];
                else if (k < 53)  w = W_ih0[orig * 3 + (k - 50)];
                else if (k == 53) w = b_ih0[orig] + b_hh0[orig];
            } else {
                if (k < 50)        w = W_ih1[orig * 50 + k];
                else if (k < 100)  w = W_hh1[orig * 50 + (k - 50)];
                else if (k == 100) w = b_ih1[orig] + b_hh1[orig];
            }
        }
        unsigned short h = f2bf(w);
        v[jj] = (short)(ishi ? h : f2bf(w - bf2f(h)));
    }
    *(short8*)&ws[((size_t)fid * 64 + lane) * 8] = v;
}

// ---------------- main kernel: fused MFMA+cell, ONE barrier per step ----------------
// Occupancy is exhausted (5 failed attempts; allocator law: targets ~2x stated min;
// only launch_bounds(512,2) -> 128 VGPR compiles clean; HW never co-schedules a 2nd
// block). This round attacks the structure instead: cell computed IN the MFMA wave
// via 4x4 lane transpose of the accumulator (gates are lane-adjacent after the
// unit-major weight permutation). Double-buffered A state (cur/nxt) makes one
// barrier per step race-free: reads from [cur], all writes to [nxt].
__global__ __launch_bounds__(NTH, 2) void lstm_mfma_v12(
    const float* __restrict__ x,
    const unsigned short* __restrict__ ws,
    const float* __restrict__ fc_w, const float* __restrict__ fc_b,
    float* __restrict__ out)
{
    __shared__ unsigned short A0hi[2][16 * A0S], A0lo[2][16 * A0S];
    __shared__ unsigned short A1hi[2][16 * A1S], A1lo[2][16 * A1S];
    __shared__ float hBf[NB * 52];     // final-step hB (fp32) for the FC

    const int tid = threadIdx.x;
    const int lane = tid & 63;
    const int n16 = lane & 15;
    const int q4  = lane >> 4;
    const int wid = tid >> 6;          // wave 0..7
    const int jb  = lane & 3;          // batch-within-quad after transpose
    const int ul  = (lane >> 2) & 3;   // unit-within-tile
    const int b0  = blockIdx.x * NB;

    // ---- zero BOTH buffers (rows 8..15, k-pad, and initial h/x/hB = 0) ----
    for (int i = tid; i < 2 * 16 * A0S; i += NTH) { A0hi[0][i] = 0; A0lo[0][i] = 0; }
    for (int i = tid; i < 2 * 16 * A1S; i += NTH) { A1hi[0][i] = 0; A1lo[0][i] = 0; }
    __syncthreads();
    if (tid < NB) {                    // constant-1 bias columns, both buffers
        A0hi[0][tid * A0S + 53]  = 0x3F80;
        A0hi[1][tid * A0S + 53]  = 0x3F80;
        A1hi[0][tid * A1S + 100] = 0x3F80;
        A1hi[1][tid * A1S + 100] = 0x3F80;
    }

    // ---- B-fragments from ws; round-9 tile distribution ----
    // L0: waves 0-2, tiles wid+3i (5,4,4); L1: waves 3-7, tiles (wid-3)+5i (3,3,3,2,2)
    const short8* wsf = (const short8*)ws;
    short8 f0h[5][2], f0l[5][2];
    short8 f1h[3][4], f1l[3][4];
    if (wid < 3) {
        #pragma unroll
        for (int i = 0; i < 5; ++i) {
            const int nt = wid + 3 * i;
            const bool nv = (nt < NTILES);
            const size_t gbase = (size_t)(nv ? nt : 0) * 12 * 64 + lane;
            #pragma unroll
            for (int kt = 0; kt < 2; ++kt) {
                f0h[i][kt] = nv ? wsf[gbase + (size_t)(kt * 2 + 0) * 64] : short8{};
                f0l[i][kt] = nv ? wsf[gbase + (size_t)(kt * 2 + 1) * 64] : short8{};
            }
        }
    } else {
        #pragma unroll
        for (int i = 0; i < 3; ++i) {
            const int nt = (wid - 3) + 5 * i;
            const bool nv = (nt < NTILES);
            const size_t gbase = (size_t)(nv ? nt : 0) * 12 * 64 + lane;
            #pragma unroll
            for (int kt = 0; kt < 4; ++kt) {
                f1h[i][kt] = nv ? wsf[gbase + (size_t)(4 + kt * 2 + 0) * 64] : short8{};
                f1l[i][kt] = nv ? wsf[gbase + (size_t)(4 + kt * 2 + 1) * 64] : short8{};
            }
        }
    }

    // ---- per-lane cell state: c for (unit = nt*4+ul, batch = q4*4+jb), per owned tile ----
    float c0s[5] = {0.f, 0.f, 0.f, 0.f, 0.f};
    float c1s[3] = {0.f, 0.f, 0.f};
    const bool cellLane = (q4 < 2);    // batches 0..7 only

    // ---- x-writer role: wave 7, lanes 32..55 (q4>=2: no cell duty) ----
    float xv = 0.f;
    size_t xbase = 0;
    int xb = 0, xc = 0;
    const bool xw = (wid == 7) && (lane >= 32) && (lane < 32 + NB * 3);
    if (xw) {
        int i = lane - 32;
        xb = i / 3; xc = i - xb * 3;
        xbase = (size_t)(b0 + xb) * (TT * 3);
        float x0 = x[xbase + xc];                    // t = 0 -> buffer 0
        unsigned short h = f2bf(x0);
        A0hi[0][xb * A0S + 50 + xc] = h;
        A0lo[0][xb * A0S + 50 + xc] = f2bf(x0 - bf2f(h));
        xv = x[xbase + 3 + xc];                      // prefetch x(1)
    }
    __syncthreads();

    // ================= MAIN LOOP: 1 barrier per iteration =================
    // iter t: L0 waves compute h0(t) [t<TT]; L1 waves compute hB(t-1) [t>0].
    // All reads from buffer cur=t&1; all writes to nxt=cur^1.
    for (int t = 0; t <= TT; ++t) {
        const int cur = t & 1, nxt = cur ^ 1;

        if (wid < 3) {
            if (t < TT) {
                short8 a0h_[2], a0l_[2];
                #pragma unroll
                for (int kt = 0; kt < 2; ++kt) {
                    a0h_[kt] = *(const short8*)&A0hi[cur][n16 * A0S + kt * 32 + q4 * 8];
                    a0l_[kt] = *(const short8*)&A0lo[cur][n16 * A0S + kt * 32 + q4 * 8];
                }
                #pragma unroll
                for (int i = 0; i < 5; ++i) {
                    const int nt = wid + 3 * i;
                    if (nt < NTILES) {
                        f32x4 aa = {0.f,0.f,0.f,0.f}, ab = {0.f,0.f,0.f,0.f};
                        aa = __builtin_amdgcn_mfma_f32_16x16x32_bf16(a0h_[0], f0h[i][0], aa, 0, 0, 0);
                        aa = __builtin_amdgcn_mfma_f32_16x16x32_bf16(a0l_[0], f0h[i][0], aa, 0, 0, 0);
                        aa = __builtin_amdgcn_mfma_f32_16x16x32_bf16(a0h_[0], f0l[i][0], aa, 0, 0, 0);
                        ab = __builtin_amdgcn_mfma_f32_16x16x32_bf16(a0h_[1], f0h[i][1], ab, 0, 0, 0);
                        ab = __builtin_amdgcn_mfma_f32_16x16x32_bf16(a0l_[1], f0h[i][1], ab, 0, 0, 0);
                        ab = __builtin_amdgcn_mfma_f32_16x16x32_bf16(a0h_[1], f0l[i][1], ab, 0, 0, 0);
                        f32x4 acc = aa + ab;
                        // ---- 4x4 lane/reg transpose within each 4-lane group ----
                        // result w[r] = gate r of (unit nt*4+ul, batch q4*4+jb)
                        float v0 = acc[0], v1 = acc[1], v2 = acc[2], v3 = acc[3];
                        float A = __shfl_xor(v0, 1), B = __shfl_xor(v1, 1);
                        float C = __shfl_xor(v2, 1), D = __shfl_xor(v3, 1);
                        float t0 = (jb & 1) ? B : v0, t1 = (jb & 1) ? v1 : A;
                        float t2 = (jb & 1) ? D : v2, t3 = (jb & 1) ? v3 : C;
                        float E = __shfl_xor(t0, 2), F = __shfl_xor(t1, 2);
                        float G = __shfl_xor(t2, 2), H = __shfl_xor(t3, 2);
                        float w0 = (jb & 2) ? G : t0, w1 = (jb & 2) ? H : t1;
                        float w2 = (jb & 2) ? t2 : E, w3 = (jb & 2) ? t3 : F;
                        // ---- cell in-wave ----
                        const int unit = nt * 4 + ul;
                        if (cellLane && unit < HH) {
                            float ii = fast_sigmoid(w0), ff = fast_sigmoid(w1);
                            float gg = fast_tanh(w2),    oo = fast_sigmoid(w3);
                            c0s[i] = ff * c0s[i] + ii * gg;
                            float h = oo * fast_tanh(c0s[i]);
                            unsigned short hh = f2bf(h);
                            unsigned short hl = f2bf(h - bf2f(hh));
                            const int batch = q4 * 4 + jb;
                            A0hi[nxt][batch * A0S + unit] = hh;   // layer0 recurrent
                            A0lo[nxt][batch * A0S + unit] = hl;
                            A1hi[nxt][batch * A1S + unit] = hh;   // layer1 input
                            A1lo[nxt][batch * A1S + unit] = hl;
                        }
                    }
                }
            }
        } else {
            if (t > 0) {
                short8 a1h_[4], a1l_[4];
                #pragma unroll
                for (int kt = 0; kt < 4; ++kt) {
                    a1h_[kt] = *(const short8*)&A1hi[cur][n16 * A1S + kt * 32 + q4 * 8];
                    a1l_[kt] = *(const short8*)&A1lo[cur][n16 * A1S + kt * 32 + q4 * 8];
                }
                #pragma unroll
                for (int i = 0; i < 3; ++i) {
                    const int nt = (wid - 3) + 5 * i;
                    if (nt < NTILES) {
                        f32x4 aa = {0.f,0.f,0.f,0.f}, ab = {0.f,0.f,0.f,0.f};
                        #pragma unroll
                        for (int kt = 0; kt < 2; ++kt) {
                            aa = __builtin_amdgcn_mfma_f32_16x16x32_bf16(a1h_[kt], f1h[i][kt], aa, 0, 0, 0);
                            aa = __builtin_amdgcn_mfma_f32_16x16x32_bf16(a1l_[kt], f1h[i][kt], aa, 0, 0, 0);
                            aa = __builtin_amdgcn_mfma_f32_16x16x32_bf16(a1h_[kt], f1l[i][kt], aa, 0, 0, 0);
                        }
                        #pragma unroll
                        for (int kt = 2; kt < 4; ++kt) {
                            ab = __builtin_amdgcn_mfma_f32_16x16x32_bf16(a1h_[kt], f1h[i][kt], ab, 0, 0, 0);
                            ab = __builtin_amdgcn_mfma_f32_16x16x32_bf16(a1l_[kt], f1h[i][kt], ab, 0, 0, 0);
                            ab = __builtin_amdgcn_mfma_f32_16x16x32_bf16(a1h_[kt], f1l[i][kt], ab, 0, 0, 0);
                        }
                        f32x4 acc = aa + ab;
                        float v0 = acc[0], v1 = acc[1], v2 = acc[2], v3 = acc[3];
                        float A = __shfl_xor(v0, 1), B = __shfl_xor(v1, 1);
                        float C = __shfl_xor(v2, 1), D = __shfl_xor(v3, 1);
                        float t0 = (jb & 1) ? B : v0, t1 = (jb & 1) ? v1 : A;
                        float t2 = (jb & 1) ? D : v2, t3 = (jb & 1) ? v3 : C;
                        float E = __shfl_xor(t0, 2), F = __shfl_xor(t1, 2);
                        float G = __shfl_xor(t2, 2), H = __shfl_xor(t3, 2);
                        float w0 = (jb & 2) ? G : t0, w1 = (jb & 2) ? H : t1;
                        float w2 = (jb & 2) ? t2 : E, w3 = (jb & 2) ? t3 : F;
                        const int unit = nt * 4 + ul;
                        if (cellLane && unit < HH) {
                            float ii = fast_sigmoid(w0), ff = fast_sigmoid(w1);
                            float gg = fast_tanh(w2),    oo = fast_sigmoid(w3);
                            c1s[i] = ff * c1s[i] + ii * gg;
                            float h = oo * fast_tanh(c1s[i]);
                            unsigned short hh = f2bf(h);
                            unsigned short hl = f2bf(h - bf2f(hh));
                            const int batch = q4 * 4 + jb;
                            A1hi[nxt][batch * A1S + 50 + unit] = hh;  // recurrent hB
                            A1lo[nxt][batch * A1S + 50 + unit] = hl;
                            if (t == TT) hBf[batch * 52 + unit] = h;
                        }
                    }
                }
            }
            if (xw && t < TT) {                          // x(t+1) -> nxt buffer
                unsigned short h = f2bf(xv);
                A0hi[nxt][xb * A0S + 50 + xc] = h;
                A0lo[nxt][xb * A0S + 50 + xc] = f2bf(xv - bf2f(h));
                int tn = (t + 2 < TT) ? (t + 2) : (TT - 1);
                xv = x[xbase + tn * 3 + xc];
            }
        }
        __syncthreads();
    }

    // ======== final FC ========
    if (tid < NB * 3) {
        int bb = tid / 3, o = tid - bb * 3;
        float a = fc_b[o];
        #pragma unroll
        for (int uu = 0; uu < HH; ++uu)
            a += hBf[bb * 52 + uu] * fc_w[o * HH + uu];
        out[(size_t)(b0 + bb) * 3 + o] = a;
    }
}

extern "C" void kernel_launch(void* const* d_in, const int* in_sizes, int n_in,
                              void* d_out, int out_size, void* d_ws, size_t ws_size,
                              hipStream_t stream) {
    const float* x     = (const float*)d_in[0];
    const float* W_ih0 = (const float*)d_in[1];
    const float* W_hh0 = (const float*)d_in[2];
    const float* b_ih0 = (const float*)d_in[3];
    const float* b_hh0 = (const float*)d_in[4];
    const float* W_ih1 = (const float*)d_in[5];
    const float* W_hh1 = (const float*)d_in[6];
    const float* b_ih1 = (const float*)d_in[7];
    const float* b_hh1 = (const float*)d_in[8];
    const float* fc_w  = (const float*)d_in[9];
    const float* fc_b  = (const float*)d_in[10];
    float* out = (float*)d_out;
    unsigned short* ws = (unsigned short*)d_ws;   // needs NFRAG*64*16 B = 156 KB

    const int prepN = NFRAG * 64;
    prep_frags<<<(prepN + 255) / 256, 256, 0, stream>>>(
        W_ih0, W_hh0, b_ih0, b_hh0, W_ih1, W_hh1, b_ih1, b_hh1, ws);

    const int B = 2048;
    dim3 grid(B / NB), block(NTH);
    lstm_mfma_v12<<<grid, block, 0, stream>>>(x, ws, fc_w, fc_b, out);
}